// Round 1
// 545.170 us; speedup vs baseline: 2.7945x; 2.7945x over previous
//
#include <hip/hip_runtime.h>

#define NPIX 262144   // B*H*H = 4*256*256
#define M1C 4096
#define M2C 512
#define E1C 65536
#define E2C 8192

// ---- workspace layout (4-byte element offsets; ints and floats share the space) ----
// zeroed region (int histograms only):
constexpr int IOFF_H1   = 0;                 // 4096
constexpr int IOFF_HC2  = IOFF_H1  + M1C;    // 512
constexpr int IOFF_HE1  = IOFF_HC2 + M2C;    // 4096
constexpr int IOFF_HE2  = IOFF_HE1 + M1C;    // 512
constexpr int ZEROI_END = IOFF_HE2 + M2C;    // 9216 elements

// scan outputs (written each call, no zeroing needed):
constexpr int IOFF_ST1   = ZEROI_END;              // 4097
constexpr int IOFF_CU1   = IOFF_ST1  + M1C + 1;    // 4096
constexpr int IOFF_STC2  = IOFF_CU1  + M1C;        // 513
constexpr int IOFF_CUC2  = IOFF_STC2 + M2C + 1;    // 512
constexpr int IOFF_STE1  = IOFF_CUC2 + M2C;        // 4097
constexpr int IOFF_CUE1  = IOFF_STE1 + M1C + 1;    // 4096
constexpr int IOFF_STE2  = IOFF_CUE1 + M1C;        // 513
constexpr int IOFF_CUE2  = IOFF_STE2 + M2C + 1;    // 512
constexpr int IOFF_PLIST = IOFF_CUE2 + M2C;        // 262144 pixel indices
constexpr int IOFF_R2L   = IOFF_PLIST + NPIX;      // 4096 row indices
constexpr int IOFF_E1L   = IOFF_R2L + M1C;         // 65536 edge src
constexpr int IOFF_E2L   = IOFF_E1L + E1C;         // 8192 edge src
constexpr int IEND       = IOFF_E2L + E2C;

// float scratch:
constexpr int OFF_S1CR  = IEND;                    // 4096*4 raw coord sums
constexpr int OFF_C1    = OFF_S1CR + M1C*4;        // 4096 pixel counts (float)
constexpr int OFF_X1CAT = OFF_C1 + M1C;            // 4096*68
constexpr int OFF_H0    = OFF_X1CAT + M1C*68;      // 4096*100
constexpr int OFF_H1F   = OFF_H0 + M1C*100;        // 4096*100
constexpr int OFF_X1FC  = OFF_H1F + M1C*100;       // 4096*64
constexpr int OFF_X1    = OFF_X1FC + M1C*64;       // 4096*64
constexpr int OFF_GM1   = OFF_X1 + M1C*64;         // 4096*64 (edge means)
constexpr int OFF_X2CAT = OFF_GM1 + M1C*64;        // 512*68
constexpr int OFF_X2FC  = OFF_X2CAT + M2C*68;      // 512*64
constexpr int OFF_X2    = OFF_X2FC + M2C*64;       // 512*64
constexpr int OFF_GM2   = OFF_X2 + M2C*64;         // 512*64
constexpr int OFF_JSF1  = OFF_GM2 + M2C*64;        // 4096*20
constexpr int OFF_JSF2  = OFF_JSF1 + M1C*20;       // 512*20

// ---------------- fused histograms: cluster1(pixels), cluster2(rows), edges1/2 dst ----------------
__global__ __launch_bounds__(256) void build_hist(
    const int* __restrict__ c1, const int* __restrict__ c2,
    const int* __restrict__ e1, const int* __restrict__ e2, int* __restrict__ wsI) {
  int i = blockIdx.x*256 + threadIdx.x;
  if (i < NPIX) {
    atomicAdd(&wsI[IOFF_H1 + c1[i]], 1);
  } else if (i < NPIX + M1C) {
    atomicAdd(&wsI[IOFF_HC2 + c2[i - NPIX]], 1);
  } else if (i < NPIX + M1C + E1C) {
    int e = i - NPIX - M1C;
    atomicAdd(&wsI[IOFF_HE1 + e1[E1C + e]], 1);
  } else {
    int e = i - NPIX - M1C - E1C;
    atomicAdd(&wsI[IOFF_HE2 + e2[E2C + e]], 1);
  }
}

// ---------------- exclusive scan, one block per histogram (4 blocks, 1024 thr) ----------------
__global__ __launch_bounds__(1024) void scan_kernel(int* __restrict__ wsI) {
  const int* hist; int* start; int* curs; int n;
  if (blockIdx.x == 0)      { hist = wsI+IOFF_H1;  start = wsI+IOFF_ST1;  curs = wsI+IOFF_CU1;  n = M1C; }
  else if (blockIdx.x == 1) { hist = wsI+IOFF_HC2; start = wsI+IOFF_STC2; curs = wsI+IOFF_CUC2; n = M2C; }
  else if (blockIdx.x == 2) { hist = wsI+IOFF_HE1; start = wsI+IOFF_STE1; curs = wsI+IOFF_CUE1; n = M1C; }
  else                      { hist = wsI+IOFF_HE2; start = wsI+IOFF_STE2; curs = wsI+IOFF_CUE2; n = M2C; }
  __shared__ int part[1024];
  int t = threadIdx.x, base = t*4, sum = 0;
  int loc0, loc1, loc2, loc3;
  loc0 = sum; sum += (base+0 < n) ? hist[base+0] : 0;
  loc1 = sum; sum += (base+1 < n) ? hist[base+1] : 0;
  loc2 = sum; sum += (base+2 < n) ? hist[base+2] : 0;
  loc3 = sum; sum += (base+3 < n) ? hist[base+3] : 0;
  part[t] = sum;
  __syncthreads();
  for (int off = 1; off < 1024; off <<= 1) {
    int v = (t >= off) ? part[t-off] : 0;
    __syncthreads();
    part[t] += v;
    __syncthreads();
  }
  int excl = (t == 0) ? 0 : part[t-1];
  if (base+0 < n) { start[base+0] = excl+loc0; curs[base+0] = excl+loc0; }
  if (base+1 < n) { start[base+1] = excl+loc1; curs[base+1] = excl+loc1; }
  if (base+2 < n) { start[base+2] = excl+loc2; curs[base+2] = excl+loc2; }
  if (base+3 < n) { start[base+3] = excl+loc3; curs[base+3] = excl+loc3; }
  if (t == 0) start[n] = part[1023];
}

// ---------------- fused scatter into bins ----------------
__global__ __launch_bounds__(256) void scatter_all(
    const int* __restrict__ c1, const int* __restrict__ c2,
    const int* __restrict__ e1, const int* __restrict__ e2, int* __restrict__ wsI) {
  int i = blockIdx.x*256 + threadIdx.x;
  if (i < NPIX) {
    int s = c1[i];
    int pos = atomicAdd(&wsI[IOFF_CU1 + s], 1);
    wsI[IOFF_PLIST + pos] = i;
  } else if (i < NPIX + M1C) {
    int r = i - NPIX;
    int s = c2[r];
    int pos = atomicAdd(&wsI[IOFF_CUC2 + s], 1);
    wsI[IOFF_R2L + pos] = r;
  } else if (i < NPIX + M1C + E1C) {
    int e = i - NPIX - M1C;
    int d = e1[E1C + e];
    int pos = atomicAdd(&wsI[IOFF_CUE1 + d], 1);
    wsI[IOFF_E1L + pos] = e1[e];           // store src row
  } else {
    int e = i - NPIX - M1C - E1C;
    int d = e2[E2C + e];
    int pos = atomicAdd(&wsI[IOFF_CUE2 + d], 1);
    wsI[IOFF_E2L + pos] = e2[e];
  }
}

// ---------------- conv3x3 recomputed inside per-cluster gather; emits x1cat + raw coord sums ----------------
__global__ __launch_bounds__(256) void gather_conv(
    const float* __restrict__ img, const float* __restrict__ cw, const float* __restrict__ cb,
    const int* __restrict__ start, const int* __restrict__ plist,
    float* __restrict__ x1cat, float* __restrict__ s1c_raw, float* __restrict__ c1f,
    float* __restrict__ jsf1) {
  int s = blockIdx.x;
  int tid = threadIdx.x;
  int q = tid >> 6, c = tid & 63;
  __shared__ float wsh[1728];               // (3,3,3,64) HWIO
  for (int t = tid; t < 1728; t += 256) wsh[t] = cw[t];
  __syncthreads();
  float wreg[27];                           // lane c's 27 weights: wsh[k*64+c], k=tap*3+ci
  #pragma unroll
  for (int k = 0; k < 27; ++k) wreg[k] = wsh[k*64 + c];
  __syncthreads();                          // wsh reads done; safe to reuse as reduction buffer

  int p0 = start[s], p1 = start[s+1];
  float acc = 0.f, sy = 0.f, sx = 0.f, syy = 0.f, sxx = 0.f;
  for (int p = p0 + q; p < p1; p += 4) {
    int n = plist[p];
    int b = n >> 16, pp = n & 65535, i = pp >> 8, j = pp & 255;
    #pragma unroll
    for (int di = 0; di < 3; ++di) {
      int y = i + di - 1;
      if ((unsigned)y >= 256u) continue;
      #pragma unroll
      for (int dj = 0; dj < 3; ++dj) {
        int x = j + dj - 1;
        if ((unsigned)x >= 256u) continue;
        int base = ((b << 16) + (y << 8) + x) * 3;
        float v0 = img[base], v1 = img[base+1], v2 = img[base+2];
        int k = (di*3 + dj)*3;
        acc = fmaf(v0, wreg[k],   acc);
        acc = fmaf(v1, wreg[k+1], acc);
        acc = fmaf(v2, wreg[k+2], acc);
      }
    }
    float yi = i * (1.0f/256.0f), xj = j * (1.0f/256.0f);
    sy += yi; sx += xj; syy += yi*yi; sxx += xj*xj;
  }
  float (*red)[72] = reinterpret_cast<float(*)[72]>(wsh);
  red[q][c] = acc;
  if (c == 0) { red[q][64] = sy; red[q][65] = sx; red[q][66] = syy; red[q][67] = sxx; }
  __syncthreads();
  int count = p1 - p0;
  if (tid < 68) {
    float tot = red[0][tid] + red[1][tid] + red[2][tid] + red[3][tid];
    float inv = 1.0f / fmaxf((float)count, 1.0f);
    if (tid < 64) {
      x1cat[s*68 + tid] = count ? tot*inv + cb[tid] : 0.0f;   // bias only if non-empty
    } else {
      float mean = tot * inv;
      x1cat[s*68 + tid] = mean;
      s1c_raw[s*4 + (tid-64)] = tot;                          // raw sums for level-2 aggregation
      if (tid == 64) jsf1[s*20 + 18] = mean;
      if (tid == 65) jsf1[s*20 + 19] = mean;
    }
  }
  if (tid == 0) c1f[s] = (float)count;
}

// ---------------- dense layer: C[M,N] = (relu?)(A[M,K] @ W[K,N] + b) ----------------
template<int RELU>
__global__ __launch_bounds__(256) void fc_kernel(
    const float* __restrict__ A, const float* __restrict__ W, const float* __restrict__ bias,
    float* __restrict__ C, int M, int K, int N, int ldc) {
  int idx = blockIdx.x*256 + threadIdx.x;
  if (idx >= M*N) return;
  int r = idx / N, c = idx - r*N;
  float acc = bias[c];
  const float* a = A + r*K;
  for (int k = 0; k < K; ++k) acc = fmaf(a[k], W[k*N + c], acc);
  if (RELU) acc = fmaxf(acc, 0.0f);
  C[r*ldc + c] = acc;
}

// ---------------- per-dst edge gather -> neighbor mean (no atomics) ----------------
__global__ __launch_bounds__(64) void edge_gather(
    const int* __restrict__ start, const int* __restrict__ elist,
    const float* __restrict__ xin, float* __restrict__ gmean) {
  int d = blockIdx.x, c = threadIdx.x;
  int p0 = start[d], p1 = start[d+1];
  float acc = 0.f;
  for (int p = p0; p < p1; ++p) acc += xin[elist[p]*64 + c];
  gmean[d*64 + c] = acc / fmaxf((float)(p1 - p0), 1.0f);
}

// ---------------- graph conv combine: out = gmean @ wn + xin @ ws + b ----------------
__global__ __launch_bounds__(256) void gc_combine(
    const float* __restrict__ gmean, const float* __restrict__ xin,
    const float* __restrict__ wn, const float* __restrict__ wsf, const float* __restrict__ bias,
    float* __restrict__ xout, float* __restrict__ out_f, int M) {
  int idx = blockIdx.x*256 + threadIdx.x;
  if (idx >= M*64) return;
  int r = idx >> 6, c = idx & 63;
  float acc = bias[c];
  const float* gmr = gmean + r*64;
  const float* xr  = xin + r*64;
  for (int k = 0; k < 64; ++k)
    acc += gmr[k]*wn[k*64 + c] + xr[k]*wsf[k*64 + c];
  xout[idx] = acc;
  out_f[idx] = acc;
}

// ---------------- level-2 pooling: x1 row means + pixel-weighted coord means ----------------
__global__ __launch_bounds__(64) void pool_l2(
    const int* __restrict__ startc2, const int* __restrict__ r2list,
    const float* __restrict__ x1, const float* __restrict__ s1c_raw, const float* __restrict__ c1f,
    float* __restrict__ x2cat, float* __restrict__ jsf2) {
  int s2 = blockIdx.x, c = threadIdx.x;
  int p0 = startc2[s2], p1 = startc2[s2+1];
  int k = c & 3;
  float acc = 0.f, sc = 0.f, cnt = 0.f;
  for (int p = p0; p < p1; ++p) {
    int r = r2list[p];
    acc += x1[r*64 + c];
    sc  += s1c_raw[r*4 + k];
    cnt += c1f[r];
  }
  float invr = 1.0f / fmaxf((float)(p1 - p0), 1.0f);
  x2cat[s2*68 + c] = acc * invr;
  if (c < 4) {
    float mean = sc / fmaxf(cnt, 1.0f);
    x2cat[s2*68 + 64 + c] = mean;
    if (c == 0) jsf2[s2*20 + 18] = mean;
    if (c == 1) jsf2[s2*20 + 19] = mean;
  }
}

// ---------------- quadratic render: r1/r2 per pixel ----------------
__global__ __launch_bounds__(256) void render_kernel(
    const int* __restrict__ cluster1, const int* __restrict__ cluster2,
    const float* __restrict__ jsf1, const float* __restrict__ jsf2,
    float* __restrict__ r1, float* __restrict__ r2) {
  int n = blockIdx.x*256 + threadIdx.x;
  int p = n & 65535, i = p >> 8, j = p & 255;
  float gy = i * (1.0f/256.0f), gx = j * (1.0f/256.0f);
  int s = cluster1[n];
  {
    const float* f = jsf1 + s*20;
    float dx = gy - f[0], dy = gx - f[1];
    #pragma unroll
    for (int c = 0; c < 3; ++c) {
      const float* pr = f + 2 + c*6;
      float v = pr[0] + pr[1]*dx + pr[2]*dy + pr[3]*dx*dx + pr[4]*dy*dy + pr[5]*dx*dy;
      r1[n*3 + c] = v;
    }
  }
  int s2 = cluster2[s];
  {
    const float* f = jsf2 + s2*20;
    float dx = gy - f[0], dy = gx - f[1];
    #pragma unroll
    for (int c = 0; c < 3; ++c) {
      const float* pr = f + 2 + c*6;
      float v = pr[0] + pr[1]*dx + pr[2]*dy + pr[3]*dx*dx + pr[4]*dy*dy + pr[5]*dx*dy;
      r2[n*3 + c] = v;
    }
  }
}

extern "C" void kernel_launch(void* const* d_in, const int* in_sizes, int n_in,
                              void* d_out, int out_size, void* d_ws, size_t ws_size,
                              hipStream_t stream) {
  const float* img    = (const float*)d_in[0];
  const float* conv_w = (const float*)d_in[1];
  const float* conv_b = (const float*)d_in[2];
  const float* t1_wi = (const float*)d_in[3];  const float* t1_bi = (const float*)d_in[4];
  const float* t1_wh = (const float*)d_in[5];  const float* t1_bh = (const float*)d_in[6];
  const float* t1_wo = (const float*)d_in[7];  const float* t1_bo = (const float*)d_in[8];
  const float* t2_wi = (const float*)d_in[9];  const float* t2_bi = (const float*)d_in[10];
  const float* t2_wh = (const float*)d_in[11]; const float* t2_bh = (const float*)d_in[12];
  const float* t2_wo = (const float*)d_in[13]; const float* t2_bo = (const float*)d_in[14];
  const float* q_wi  = (const float*)d_in[15]; const float* q_bi  = (const float*)d_in[16];
  const float* q_wh  = (const float*)d_in[17]; const float* q_bh  = (const float*)d_in[18];
  const float* q_wo  = (const float*)d_in[19]; const float* q_bo  = (const float*)d_in[20];
  const float* gc1_wn = (const float*)d_in[21]; const float* gc1_ws = (const float*)d_in[22];
  const float* gc1_b  = (const float*)d_in[23];
  const float* gc2_wn = (const float*)d_in[24]; const float* gc2_ws = (const float*)d_in[25];
  const float* gc2_b  = (const float*)d_in[26];
  const int* cluster1 = (const int*)d_in[27];
  const int* cluster2 = (const int*)d_in[28];
  const int* edges1   = (const int*)d_in[29];
  const int* edges2   = (const int*)d_in[30];

  float* ws = (float*)d_ws;
  int*   wsI = (int*)d_ws;
  float* out  = (float*)d_out;
  float* o_r1 = out;
  float* o_r2 = out + 786432;
  float* o_x1 = out + 1572864;
  float* o_x2 = out + 1835008;

  // zero only the int histograms (36 KB)
  hipMemsetAsync(d_ws, 0, (size_t)ZEROI_END * sizeof(int), stream);

  constexpr int TOTW = NPIX + M1C + E1C + E2C;   // 339968, /256 = 1328 exact
  build_hist<<<TOTW/256, 256, 0, stream>>>(cluster1, cluster2, edges1, edges2, wsI);
  scan_kernel<<<4, 1024, 0, stream>>>(wsI);
  scatter_all<<<TOTW/256, 256, 0, stream>>>(cluster1, cluster2, edges1, edges2, wsI);

  // conv + level-1 segment means (fused, atomic-free)
  gather_conv<<<M1C, 256, 0, stream>>>(img, conv_w, conv_b,
      wsI+IOFF_ST1, wsI+IOFF_PLIST,
      ws+OFF_X1CAT, ws+OFF_S1CR, ws+OFF_C1, ws+OFF_JSF1);

  // t1 MLP: 68 -> 100 -> 100 -> 100 -> 64
  fc_kernel<1><<<(M1C*100)/256, 256, 0, stream>>>(ws+OFF_X1CAT, t1_wi, t1_bi, ws+OFF_H0, M1C, 68, 100, 100);
  fc_kernel<1><<<(M1C*100)/256, 256, 0, stream>>>(ws+OFF_H0, t1_wh,        t1_bh,     ws+OFF_H1F, M1C, 100, 100, 100);
  fc_kernel<1><<<(M1C*100)/256, 256, 0, stream>>>(ws+OFF_H1F, t1_wh+10000, t1_bh+100, ws+OFF_H0,  M1C, 100, 100, 100);
  fc_kernel<0><<<(M1C*64)/256, 256, 0, stream>>>(ws+OFF_H0, t1_wo, t1_bo, ws+OFF_X1FC, M1C, 100, 64, 64);

  // graph conv 1 (binned gather, no atomics)
  edge_gather<<<M1C, 64, 0, stream>>>(wsI+IOFF_STE1, wsI+IOFF_E1L, ws+OFF_X1FC, ws+OFF_GM1);
  gc_combine<<<(M1C*64)/256, 256, 0, stream>>>(ws+OFF_GM1, ws+OFF_X1FC,
      gc1_wn, gc1_ws, gc1_b, ws+OFF_X1, o_x1, M1C);

  // level-2 pooling (binned gather)
  pool_l2<<<M2C, 64, 0, stream>>>(wsI+IOFF_STC2, wsI+IOFF_R2L,
      ws+OFF_X1, ws+OFF_S1CR, ws+OFF_C1, ws+OFF_X2CAT, ws+OFF_JSF2);

  // t2 MLP
  fc_kernel<1><<<(M2C*100)/256, 256, 0, stream>>>(ws+OFF_X2CAT, t2_wi, t2_bi, ws+OFF_H0, M2C, 68, 100, 100);
  fc_kernel<1><<<(M2C*100)/256, 256, 0, stream>>>(ws+OFF_H0, t2_wh,        t2_bh,     ws+OFF_H1F, M2C, 100, 100, 100);
  fc_kernel<1><<<(M2C*100)/256, 256, 0, stream>>>(ws+OFF_H1F, t2_wh+10000, t2_bh+100, ws+OFF_H0,  M2C, 100, 100, 100);
  fc_kernel<0><<<(M2C*64)/256, 256, 0, stream>>>(ws+OFF_H0, t2_wo, t2_bo, ws+OFF_X2FC, M2C, 100, 64, 64);

  // graph conv 2
  edge_gather<<<M2C, 64, 0, stream>>>(wsI+IOFF_STE2, wsI+IOFF_E2L, ws+OFF_X2FC, ws+OFF_GM2);
  gc_combine<<<(M2C*64)/256, 256, 0, stream>>>(ws+OFF_GM2, ws+OFF_X2FC,
      gc2_wn, gc2_ws, gc2_b, ws+OFF_X2, o_x2, M2C);

  // q MLP on x1 -> jsf1[:,0:18]
  fc_kernel<1><<<(M1C*100)/256, 256, 0, stream>>>(ws+OFF_X1, q_wi, q_bi, ws+OFF_H0, M1C, 64, 100, 100);
  fc_kernel<1><<<(M1C*100)/256, 256, 0, stream>>>(ws+OFF_H0, q_wh,        q_bh,     ws+OFF_H1F, M1C, 100, 100, 100);
  fc_kernel<1><<<(M1C*100)/256, 256, 0, stream>>>(ws+OFF_H1F, q_wh+10000, q_bh+100, ws+OFF_H0,  M1C, 100, 100, 100);
  fc_kernel<0><<<(M1C*18)/256, 256, 0, stream>>>(ws+OFF_H0, q_wo, q_bo, ws+OFF_JSF1, M1C, 100, 18, 20);

  // q MLP on x2 -> jsf2[:,0:18]
  fc_kernel<1><<<(M2C*100)/256, 256, 0, stream>>>(ws+OFF_X2, q_wi, q_bi, ws+OFF_H0, M2C, 64, 100, 100);
  fc_kernel<1><<<(M2C*100)/256, 256, 0, stream>>>(ws+OFF_H0, q_wh,        q_bh,     ws+OFF_H1F, M2C, 100, 100, 100);
  fc_kernel<1><<<(M2C*100)/256, 256, 0, stream>>>(ws+OFF_H1F, q_wh+10000, q_bh+100, ws+OFF_H0,  M2C, 100, 100, 100);
  fc_kernel<0><<<(M2C*18)/256, 256, 0, stream>>>(ws+OFF_H0, q_wo, q_bo, ws+OFF_JSF2, M2C, 100, 18, 20);

  // renders
  render_kernel<<<NPIX/256, 256, 0, stream>>>(cluster1, cluster2, ws+OFF_JSF1, ws+OFF_JSF2, o_r1, o_r2);
}